// Round 7
// baseline (135.138 us; speedup 1.0000x reference)
//
#include <hip/hip_runtime.h>
#include <stdint.h>

// Problem: out[m,e,k] = sum_n A[m,n] * W[e,n,k]
// == GEMM C[8192,2048] = A[8192,1024] x B[1024,2048], B[n, e*32+k] = W[e,n,k]
//
// Round-11 structure: TLP-first. Five schedule variants (rounds 0-6) all
// pinned at 42-44 us / MfmaUtil ~30% regardless of pipelining -> the limiter
// is lockstep single-block-per-CU execution (LDS pipe and MFMA pipe serialize
// at barriers; epilogues of identical blocks drain C to HBM simultaneously).
// Fix per m114: cross-block wave overlap. 128x128 tile, 4 waves (2x2, wave
// tile 64x64), grid 1024 = 4 blocks/CU, __launch_bounds__(256,4) = 16
// waves/CU. A via global_load_lds double-buffer (32 KB LDS -> 4 blocks fit);
// staging of tile t+1 issued at the top of tile t (full tile of slack before
// the end-of-tile barrier drain). B fragments direct from L2 (proven
// conflict-free, keeps LDS small). No hand waitcnt/setprio/sched_barrier:
// with 4 independent blocks per CU the hardware fills stalls; compiler
// schedules locally.
// A LDS: [128 rows][8 grp][8] XOR-swizzled (grp ^ row&7), conflict-free.
// XCD: j_idx = orig&15 -> XCD c sees j in {c, c+8}: 256 B-cols = 512 KB/XCD L2.

#define M_DIM 8192
#define N_IN  1024   // reduction dim
#define E_DIM 64
#define K_DIM 32
#define J_DIM 2048   // E*K output columns

typedef __attribute__((ext_vector_type(8))) __bf16 bf16x8;
typedef __attribute__((ext_vector_type(4))) float floatx4;
typedef __attribute__((address_space(3))) unsigned short lds_u16;

__device__ inline unsigned short f2bf(float f) {
    union { float f; unsigned u; } v; v.f = f;
    unsigned u = v.u;
    u += 0x7fff + ((u >> 16) & 1);   // round-to-nearest-even
    return (unsigned short)(u >> 16);
}

// A [8192,1024] f32 -> Ab bf16 (same row-major layout). 4 elements/thread.
__global__ __launch_bounds__(256) void convert_A(const float* __restrict__ A,
                                                 unsigned short* __restrict__ Ab) {
    size_t i = (size_t)blockIdx.x * 256 + threadIdx.x;
    const float4 v = ((const float4*)A)[i];
    ushort4 o;
    o.x = f2bf(v.x); o.y = f2bf(v.y); o.z = f2bf(v.z); o.w = f2bf(v.w);
    ((ushort4*)Ab)[i] = o;
}

// W [64][1024][32] f32 -> BG[kgroup=n>>3][j=e*32+k][t=n&7] bf16  (128 x 2048 x 8).
// B fragment for 16x16x32 MFMA: lane holds B^T[col j][k = kgroup*8 + t], t=0..7
// contiguous -> one 16B load per lane, lanes j-consecutive -> coalesced.
__global__ __launch_bounds__(256) void convert_W(const float* __restrict__ W,
                                                 unsigned short* __restrict__ BG) {
    const int t   = threadIdx.x;
    const int e   = blockIdx.y;        // 0..63
    const int n0  = blockIdx.x * 64;   // 16 slabs
    const int k   = t & 31;
    const int oct = t >> 5;            // 8 octets of n within the slab
    const float* Wp = W + ((size_t)e * N_IN + n0 + oct * 8) * K_DIM + k;
    unsigned short tmp[8];
#pragma unroll
    for (int u = 0; u < 8; ++u) tmp[u] = f2bf(Wp[(size_t)u * K_DIM]);  // coalesced per u
    unsigned short* out = BG + ((size_t)((n0 >> 3) + oct) * J_DIM + e * K_DIM + k) * 8;
    ushort4 lo, hi;
    lo.x = tmp[0]; lo.y = tmp[1]; lo.z = tmp[2]; lo.w = tmp[3];
    hi.x = tmp[4]; hi.y = tmp[5]; hi.z = tmp[6]; hi.w = tmp[7];
    ((ushort4*)out)[0] = lo;
    ((ushort4*)out)[1] = hi;
}

#define GLDS(SRC, DST)                                                          \
    __builtin_amdgcn_global_load_lds(                                           \
        (const __attribute__((address_space(1))) unsigned int*)(SRC),           \
        (__attribute__((address_space(3))) unsigned int*)(DST), 16, 0, 0)

// Stage the 128x64 A-slab of K-tile T1 into LDS buffer NA (16 chunks of 1 KB;
// each wave covers 4). Lane l covers LDS slot (row=l>>3, grp=l&7), fetching
// pre-swizzled global group (l&7)^(l>>3).
#define STAGE_A(NA, T1)                                                         \
    { _Pragma("unroll")                                                         \
      for (int c = 0; c < 4; ++c)                                               \
          GLDS(gA0 + (size_t)c * (8 * N_IN) + (size_t)(T1) * 64,                \
               (NA) + wave * 2048 + c * 512); }

__global__ __launch_bounds__(256, 4) void gemm_bt(const unsigned short* __restrict__ Ab,
                                                  const unsigned short* __restrict__ BG,
                                                  float* __restrict__ C) {
    __shared__ unsigned short As0[8192];   // A tile buf0: [128 rows][8 grp][8]
    __shared__ unsigned short As1[8192];

    const int tid  = threadIdx.x;
    const int wave = tid >> 6;       // 0..3
    const int lane = tid & 63;
    const int wm = wave >> 1;        // 0..1  (M-half of 128)
    const int wn = wave & 1;         // 0..1  (N-half of 128)

    const int orig = blockIdx.x;     // 1024 blocks = 64 m x 16 j; XCD = orig%8
    const int m0 = (orig >> 4) * 128;
    const int j0 = (orig & 15) * 128;

    const int l7 = lane & 7, l15 = lane & 15, quad = lane >> 4, lrow8 = lane >> 3;

    // A staging base: rows wave*32 + c*8 + lrow8, pre-swizzled group.
    const unsigned short* gA0 = Ab + (size_t)(m0 + wave * 32 + lrow8) * N_IN
                                   + ((l7 ^ lrow8) << 3);
    const int jcol = j0 + wn * 64 + l15;      // per-lane B column

    lds_u16* cA = (lds_u16*)As0;
    lds_u16* nA = (lds_u16*)As1;

    floatx4 acc[4][4];
#pragma unroll
    for (int i = 0; i < 4; ++i)
#pragma unroll
        for (int j = 0; j < 4; ++j) acc[i][j] = (floatx4)(0.0f);

    // Fragment-read addressing (row&7 == l7 since rows step by 16).
    const int arow = (wm * 64 + l15) * 64;            // A row base (shorts)
    const int sA0  = (quad ^ l7) << 3;                // A slot-group; h flips bit 2

    // --- prologue: stage A tile 0 -------------------------------------------
    STAGE_A(cA, 0);
    __syncthreads();                  // drains staging (compiler vmcnt(0))

    for (int t = 0; t < 16; ++t) {
        // Issue next tile's staging first: full tile of compute before the
        // end-of-tile barrier drains it.
        if (t < 15) STAGE_A(nA, t + 1);

        // B fragments for both k-halves, direct from L2.
        bf16x8 bfr[2][4];
#pragma unroll
        for (int h = 0; h < 2; ++h) {
            const int kg = t * 8 + h * 4 + quad;
#pragma unroll
            for (int j = 0; j < 4; ++j)
                bfr[h][j] = *(const bf16x8*)(BG + ((size_t)kg * J_DIM + jcol + j * 16) * 8);
        }

#pragma unroll
        for (int h = 0; h < 2; ++h) {
#pragma unroll
            for (int i = 0; i < 4; ++i) {
                const bf16x8 af = *(const __attribute__((address_space(3))) bf16x8*)
                    (cA + arow + i * 1024 + (sA0 ^ (h << 5)));
#pragma unroll
                for (int j = 0; j < 4; ++j)
                    acc[i][j] = __builtin_amdgcn_mfma_f32_16x16x32_bf16(
                        af, bfr[h][j], acc[i][j], 0, 0, 0);
            }
        }
        __syncthreads();              // all waves done reading cA; staging of
                                      // t+1 (issued above) also drained here
        lds_u16* sw = cA; cA = nA; nA = sw;
    }

    // Epilogue: C/D layout col = lane&15, row = (lane>>4)*4 + reg
    const int crow = quad * 4;
#pragma unroll
    for (int i = 0; i < 4; ++i) {
#pragma unroll
        for (int j = 0; j < 4; ++j) {
            float* Cp = C + (size_t)(m0 + wm * 64 + i * 16 + crow) * J_DIM
                          + (j0 + wn * 64 + j * 16 + l15);
#pragma unroll
            for (int r = 0; r < 4; ++r)
                Cp[(size_t)r * J_DIM] = acc[i][j][r];
        }
    }
}

extern "C" void kernel_launch(void* const* d_in, const int* in_sizes, int n_in,
                              void* d_out, int out_size, void* d_ws, size_t ws_size,
                              hipStream_t stream) {
    const float* A = (const float*)d_in[0];   // [8192,1024]
    const float* W = (const float*)d_in[1];   // [64,1024,32]
    float* out = (float*)d_out;               // [8192,64,32] == [8192,2048]

    unsigned short* Ab = (unsigned short*)d_ws;                 // 16 MB
    unsigned short* BG = Ab + (size_t)M_DIM * N_IN;             // +4 MB

    convert_A<<<M_DIM * N_IN / (256 * 4), 256, 0, stream>>>(A, Ab);
    convert_W<<<dim3(N_IN / 64, E_DIM), 256, 0, stream>>>(W, BG);
    gemm_bt<<<dim3(1024), dim3(256), 0, stream>>>(Ab, BG, out);
}

// Round 9
// 129.504 us; speedup vs baseline: 1.0435x; 1.0435x over previous
//
#include <hip/hip_runtime.h>
#include <stdint.h>

// Problem: out[m,e,k] = sum_n A[m,n] * W[e,n,k]
// == GEMM C[8192,2048] = A[8192,1024] x B[1024,2048], B[n, e*32+k] = W[e,n,k]
//
// Round-13 = Round-12 resubmitted byte-identical (round-8 bench was an infra
// "container failed twice"; the kernel differs from the round-6 PASS by one
// desk-verified bijective index mapping only).
//
// Round-12 = Round-10 (B-direct register ping-pong) with ONE change: XCD
// ownership inverted from j-slices to M-SLICES. Evidence: 7 schedule variants
// all pinned at 43-46 us, MfmaUtil 28-30%, FETCH+WRITE = 3.0 TB/s invariant;
// occupancy doubling changed nothing -> memory-system bound. FETCH 68 MB vs
// 16 MB unique A: j-slice XCDs stream the same A through all 8 private L2s
// (16 MB working set >> 4 MB L2 -> misses all kernel). M-slice ownership gives
// each XCD a 2 MB A slice (L2-RESIDENT) + 256 KB hot B K-slab; A is fetched
// once, B cold 4 MB, HBM traffic ~88 MB vs 133.
// Mapping: xcd=orig&7 (dispatch d -> XCD d%8), s=orig>>3;
//          m_idx = xcd*4 + (s&3), j_idx = s>>2 (bijective; 4 consecutive
//          dispatches per XCD share one B j-slab).
//
// Rest identical to round 10: A through double-buffered LDS (64 KB), B
// fragments direct from L2; register ping-pong, ONE barrier per K-tile,
// counted vmcnt/lgkm ledger, sched_barrier(0) pins, setprio around MFMA.
// A LDS: [256 rows][8 grp][8] XOR-swizzled (grp ^ row&7), conflict-free.

#define M_DIM 8192
#define N_IN  1024   // reduction dim
#define E_DIM 64
#define K_DIM 32
#define J_DIM 2048   // E*K output columns

typedef __attribute__((ext_vector_type(8))) __bf16 bf16x8;
typedef __attribute__((ext_vector_type(4))) float floatx4;
typedef __attribute__((address_space(3))) unsigned short lds_u16;

__device__ inline unsigned short f2bf(float f) {
    union { float f; unsigned u; } v; v.f = f;
    unsigned u = v.u;
    u += 0x7fff + ((u >> 16) & 1);   // round-to-nearest-even
    return (unsigned short)(u >> 16);
}

// A [8192,1024] f32 -> Ab bf16 (same row-major layout). 4 elements/thread.
__global__ __launch_bounds__(256) void convert_A(const float* __restrict__ A,
                                                 unsigned short* __restrict__ Ab) {
    size_t i = (size_t)blockIdx.x * 256 + threadIdx.x;
    const float4 v = ((const float4*)A)[i];
    ushort4 o;
    o.x = f2bf(v.x); o.y = f2bf(v.y); o.z = f2bf(v.z); o.w = f2bf(v.w);
    ((ushort4*)Ab)[i] = o;
}

// W [64][1024][32] f32 -> BG[kgroup=n>>3][j=e*32+k][t=n&7] bf16  (128 x 2048 x 8).
// B fragment for 16x16x32 MFMA: lane holds B^T[col j][k = kgroup*8 + t], t=0..7
// contiguous -> one 16B load per lane, lanes j-consecutive -> coalesced.
__global__ __launch_bounds__(256) void convert_W(const float* __restrict__ W,
                                                 unsigned short* __restrict__ BG) {
    const int t   = threadIdx.x;
    const int e   = blockIdx.y;        // 0..63
    const int n0  = blockIdx.x * 64;   // 16 slabs
    const int k   = t & 31;
    const int oct = t >> 5;            // 8 octets of n within the slab
    const float* Wp = W + ((size_t)e * N_IN + n0 + oct * 8) * K_DIM + k;
    unsigned short tmp[8];
#pragma unroll
    for (int u = 0; u < 8; ++u) tmp[u] = f2bf(Wp[(size_t)u * K_DIM]);  // coalesced per u
    unsigned short* out = BG + ((size_t)((n0 >> 3) + oct) * J_DIM + e * K_DIM + k) * 8;
    ushort4 lo, hi;
    lo.x = tmp[0]; lo.y = tmp[1]; lo.z = tmp[2]; lo.w = tmp[3];
    hi.x = tmp[4]; hi.y = tmp[5]; hi.z = tmp[6]; hi.w = tmp[7];
    ((ushort4*)out)[0] = lo;
    ((ushort4*)out)[1] = hi;
}

#define GLDS(SRC, DST)                                                          \
    __builtin_amdgcn_global_load_lds(                                           \
        (const __attribute__((address_space(1))) unsigned int*)(SRC),           \
        (__attribute__((address_space(3))) unsigned int*)(DST), 16, 0, 0)

// Stage A row-half HALF (128 rows x 64 k) of K-tile T1 into LDS buffer NA.
#define STAGE_A(NA, T1, HALF)                                                   \
    { _Pragma("unroll")                                                         \
      for (int c = 0; c < 2; ++c)                                               \
          GLDS(gA0 + (size_t)((HALF) * 128 + c * 64) * N_IN + (size_t)(T1) * 64,\
               (NA) + (HALF) * 8192 + c * 4096 + wave * 512); }

#define WAIT_VM(N) asm volatile("s_waitcnt vmcnt(" #N ")" ::: "memory")
#define LGKM(N)    asm volatile("s_waitcnt lgkmcnt(" #N ")" ::: "memory")
#define SB()       __builtin_amdgcn_sched_barrier(0)

// A fragment loads (explicit LDS address space -> ds_read_b128).
#define RD_A(DST, CA, H, IH)                                                    \
    { _Pragma("unroll")                                                         \
      for (int ii = 0; ii < 4; ++ii)                                            \
          DST[ii] = *(const __attribute__((address_space(3))) bf16x8*)          \
                    ((CA) + arow + ((IH) * 4 + ii) * 1024 + (sA0 ^ ((H) << 5))); }

// B fragment loads DIRECT from global (L2-hot), kgroup KG, 4 j-subtiles.
#define RD_BG(DST, KG)                                                          \
    { _Pragma("unroll")                                                         \
      for (int j = 0; j < 4; ++j)                                               \
          DST[j] = *(const bf16x8*)(BG + ((size_t)(KG) * J_DIM + jcol + j * 16) * 8); }

// 16-MFMA cluster on register-resident fragments (T5 setprio wrap).
#define MFMA_CL(AF, BF, IH)                                                     \
    { __builtin_amdgcn_s_setprio(1);                                            \
      _Pragma("unroll")                                                         \
      for (int ii = 0; ii < 4; ++ii) {                                          \
          _Pragma("unroll")                                                     \
          for (int j = 0; j < 4; ++j)                                           \
              acc[(IH) * 4 + ii][j] = __builtin_amdgcn_mfma_f32_16x16x32_bf16(  \
                  AF[ii], BF[j], acc[(IH) * 4 + ii][j], 0, 0, 0);               \
      }                                                                         \
      __builtin_amdgcn_s_setprio(0); }

__global__ __launch_bounds__(512, 1) void gemm_bt(const unsigned short* __restrict__ Ab,
                                                  const unsigned short* __restrict__ BG,
                                                  float* __restrict__ C) {
    __shared__ unsigned short As0[16384];   // A tile buf0: [256 rows][8 grp][8]
    __shared__ unsigned short As1[16384];

    const int tid  = threadIdx.x;
    const int wave = tid >> 6;       // 0..7
    const int lane = tid & 63;
    const int wm = wave >> 2;        // 0..1  (M-half of 256)
    const int wn = wave & 3;         // 0..3  (N-quarter of 256)

    // --- M-slice XCD ownership ----------------------------------------------
    // XCD x (= orig%8) owns m-tiles [4x, 4x+4): A slice 2 MB -> L2-resident.
    // Within an XCD, consecutive dispatches share one B j-slab (j = s>>2).
    const int orig = blockIdx.x;     // 256 blocks = 32 m x 8 j
    const int xcd  = orig & 7;
    const int s    = orig >> 3;
    const int m0 = (xcd * 4 + (s & 3)) * 256;
    const int j0 = (s >> 2) * 256;

    const int l7 = lane & 7, l15 = lane & 15, quad = lane >> 4, lrow8 = lane >> 3;

    // A staging: lane l covers LDS slot (row=l>>3, grp=l&7), fetching
    // pre-swizzled global group (l&7)^(l>>3).
    const unsigned short* gA0 = Ab + (size_t)(m0 + wave * 8 + lrow8) * N_IN
                                   + ((l7 ^ lrow8) << 3);
    const int jcol = j0 + wn * 64 + l15;      // per-lane B column

    lds_u16* cA = (lds_u16*)As0;
    lds_u16* nA = (lds_u16*)As1;

    floatx4 acc[8][4];
#pragma unroll
    for (int i = 0; i < 8; ++i)
#pragma unroll
        for (int j = 0; j < 4; ++j) acc[i][j] = (floatx4)(0.0f);

    // Fragment-read addressing
    const int arow = (wm * 128 + l15) * 64;           // A row base (shorts)
    const int sA0  = (quad ^ l7) << 3;                // A slot-group; h flips bit 2

    // --- prologue: stage A tile 0; load B(h0,0) into bfA --------------------
    bf16x8 afA[4], afB[4], bfA[4], bfB[4];
    STAGE_A(cA, 0, 0);
    STAGE_A(cA, 0, 1); SB();
    RD_BG(bfA, quad); SB();          // B(h0, t=0); stays in flight over barrier
    WAIT_VM(4); SB();                // A staging done (bfA x4 outstanding)
    __builtin_amdgcn_s_barrier(); SB();
    RD_A(afA, cA, 0, 0); SB();

    // --- main loop: 15 tiles with staging, clusters c0..c3 ------------------
    for (int t = 0; t < 15; ++t) {
        // c0: MFMA(h0,i0-3) | issue A(h0,i4-7) reads + stage A(t+1,h0)
        RD_A(afB, cA, 0, 1); SB();
        STAGE_A(nA, t + 1, 0); SB();
        LGKM(4);                      // afA ready (afB x4 left)
        WAIT_VM(2); SB();             // bfA ready (stage_h0 x2 left)
        MFMA_CL(afA, bfA, 0);

        // c1: MFMA(h0,i4-7) | issue A(h1,i0-3) reads + load B(h1,t) + stage A(t+1,h1)
        RD_A(afA, cA, 1, 0); SB();
        RD_BG(bfB, t * 8 + 4 + quad); SB();
        STAGE_A(nA, t + 1, 1); SB();
        LGKM(4); SB();                // afB ready
        MFMA_CL(afB, bfA, 1);

        // c2: MFMA(h1,i0-3) | issue A(h1,i4-7) reads + load B(h0,t+1)
        RD_A(afB, cA, 1, 1); SB();
        RD_BG(bfA, (t + 1) * 8 + quad); SB();
        LGKM(4);                      // afA ready
        WAIT_VM(6); SB();             // bfB ready (stage_h1 x2 + bfA x4 left)
        MFMA_CL(afA, bfB, 0);

        // c3: drain + recycle barrier, then issue tile-(t+1) c0 reads
        LGKM(0);                      // own ds_reads of retiring buf done
        WAIT_VM(4); SB();             // A staging of t+1 done (bfA x4 in flight)
        __builtin_amdgcn_s_barrier(); SB();
        { lds_u16* sw = cA; cA = nA; nA = sw; }
        RD_A(afA, cA, 0, 0); SB();
        MFMA_CL(afB, bfB, 1);
    }

    // --- tail tile 15 (no staging, no B prefetch of t+1) --------------------
    RD_A(afB, cA, 0, 1); SB();
    LGKM(4);
    WAIT_VM(0); SB();                 // bfA ready
    MFMA_CL(afA, bfA, 0);
    RD_A(afA, cA, 1, 0); SB();
    RD_BG(bfB, 15 * 8 + 4 + quad); SB();
    LGKM(4); SB();
    MFMA_CL(afB, bfA, 1);
    RD_A(afB, cA, 1, 1); SB();
    LGKM(4);
    WAIT_VM(0); SB();                 // bfB ready
    MFMA_CL(afA, bfB, 0);
    LGKM(0); SB();
    MFMA_CL(afB, bfB, 1);

    // Epilogue: C/D layout col = lane&15, row = (lane>>4)*4 + reg
    const int crow = quad * 4;
#pragma unroll
    for (int i = 0; i < 8; ++i) {
#pragma unroll
        for (int j = 0; j < 4; ++j) {
            float* Cp = C + (size_t)(m0 + wm * 128 + i * 16 + crow) * J_DIM
                          + (j0 + wn * 64 + j * 16 + l15);
#pragma unroll
            for (int r = 0; r < 4; ++r)
                Cp[(size_t)r * J_DIM] = acc[i][j][r];
        }
    }
}

extern "C" void kernel_launch(void* const* d_in, const int* in_sizes, int n_in,
                              void* d_out, int out_size, void* d_ws, size_t ws_size,
                              hipStream_t stream) {
    const float* A = (const float*)d_in[0];   // [8192,1024]
    const float* W = (const float*)d_in[1];   // [64,1024,32]
    float* out = (float*)d_out;               // [8192,64,32] == [8192,2048]

    unsigned short* Ab = (unsigned short*)d_ws;                 // 16 MB
    unsigned short* BG = Ab + (size_t)M_DIM * N_IN;             // +4 MB

    convert_A<<<M_DIM * N_IN / (256 * 4), 256, 0, stream>>>(A, Ab);
    convert_W<<<dim3(N_IN / 64, E_DIM), 256, 0, stream>>>(W, BG);
    gemm_bt<<<dim3(256), dim3(512), 0, stream>>>(Ab, BG, out);
}